// Round 8
// baseline (145150.757 us; speedup 1.0000x reference)
//
#include <hip/hip_runtime.h>
#include <math.h>

#define NBLK 128
#define NTHR 256
#define NPOS 3168     // 99 steps * 32 batch
#define NSTAGES 3177  // last proj-phase2 at s = 3167 + 9
#define HIDN 512
#define TT 2048
#define LL 100

__device__ __forceinline__ float aload(const float* p) {
  return __hip_atomic_load((float*)p, __ATOMIC_RELAXED, __HIP_MEMORY_SCOPE_AGENT);
}
__device__ __forceinline__ void astore(float* p, float v) {
  __hip_atomic_store(p, v, __ATOMIC_RELAXED, __HIP_MEMORY_SCOPE_AGENT);
}
__device__ __forceinline__ float wsum(float v) {
#pragma unroll
  for (int o = 32; o; o >>= 1) v += __shfl_xor(v, o);
  return v;
}
__device__ __forceinline__ float wmax(float v) {
#pragma unroll
  for (int o = 32; o; o >>= 1) v = fmaxf(v, __shfl_xor(v, o));
  return v;
}
__device__ __forceinline__ float sigm(float x) { return 1.f / (1.f + expf(-x)); }

extern "C" __global__ void speller_init(float* ws) {
  const int i = blockIdx.x * blockDim.x + threadIdx.x;
  if (i < 3328) ws[i] = 0.f;  // arrive flags (256 ints) + h double buffers (3072 floats)
}

// NOTE: launched as a PLAIN kernel (not hipLaunchCooperativeKernel).
// The grid barrier is hand-rolled flag sync; 128 blocks on 256 CUs are
// always co-resident. Cooperative launch validation rejected the
// high-VGPR variants silently (r3/r7 zero-output failures).
// launch_bounds(256,2): VGPR cap 256/thread, overflow goes to AGPR (on-chip).
extern "C" __global__ __launch_bounds__(NTHR, 2)
void speller_main(const float* __restrict__ ctx_t, const int* __restrict__ gt,
                  const float* __restrict__ emb, const float* __restrict__ w_out,
                  const float* __restrict__ b_out,
                  const float* __restrict__ wi0, const float* __restrict__ wh0,
                  const float* __restrict__ bi0, const float* __restrict__ bh0,
                  const float* __restrict__ wi1, const float* __restrict__ wh1,
                  const float* __restrict__ bi1, const float* __restrict__ bh1,
                  const float* __restrict__ wi2, const float* __restrict__ wh2,
                  const float* __restrict__ bi2, const float* __restrict__ bh2,
                  float* __restrict__ out, float* __restrict__ ws)
{
  const int bid = blockIdx.x, tid = threadIdx.x;
  const int lane = tid & 63, wv = tid >> 6;   // 4 waves
  const int ub = bid * 4;  // this block's 4 hidden units (per layer)

  // ---------------- workspace layout (195,968 floats = 783.9 KB) ----------------
  int*   arrive   = (int*)ws;               // [256] (128 used)
  float* h_buf    = ws + 256;               // [2][3][512]
  float* rnn_ring = ws + 3328;              // [8][512]
  float* ctx_ring = ws + 7424;              // [64][512]
  float* e_ring   = ws + 40192;             // [2][2048]
  float* w_ring   = ws + 44288;             // [2][2048]
  float* P_ring   = ws + 48384;             // [2][128][512]
  float* Q_ring   = ws + 179456;            // [2][16][512]
  float* z_ring   = ws + 195840;            // [2][64]

  __shared__ float sro[HIDN];   // rnn_out for attention energies
  __shared__ float swex[16];    // this block's 16 attention weights (phase C)
  __shared__ float gates[48];   // l*16 + g*4 + q
  __shared__ float csto[12];    // cell state, 4 units x 3 layers

  if (tid < 12) csto[tid] = 0.f;

  // ---------------- weight preload into registers ----------------
  // Wave w holds gate w (4 unit-rows) of ALL 3 layers:
  //   wreg[0..3]  = layer0 gate w rows (17 chunks: emb 1, ctx 8, h0 8)
  //   wreg[4..7]  = layer1 gate w rows (16 chunks: h0 8, h1 8)
  //   wreg[8..11] = layer2 gate w rows (16 chunks: h1 8, h2 8)
  float wreg[12][17];
  float bsum[12];
#pragma unroll
  for (int q = 0; q < 4; ++q) {
    const int R = wv * 512 + ub + q;
#pragma unroll
    for (int k = 0; k < 9; ++k) wreg[q][k] = wi0[(size_t)R * 576 + k * 64 + lane];
#pragma unroll
    for (int k = 0; k < 8; ++k) wreg[q][9 + k] = wh0[(size_t)R * 512 + k * 64 + lane];
    bsum[q] = bi0[R] + bh0[R];
#pragma unroll
    for (int k = 0; k < 8; ++k) wreg[4 + q][k]     = wi1[(size_t)R * 512 + k * 64 + lane];
#pragma unroll
    for (int k = 0; k < 8; ++k) wreg[4 + q][8 + k] = wh1[(size_t)R * 512 + k * 64 + lane];
    wreg[4 + q][16] = 0.f;
    bsum[4 + q] = bi1[R] + bh1[R];
#pragma unroll
    for (int k = 0; k < 8; ++k) wreg[8 + q][k]     = wi2[(size_t)R * 512 + k * 64 + lane];
#pragma unroll
    for (int k = 0; k < 8; ++k) wreg[8 + q][8 + k] = wh2[(size_t)R * 512 + k * 64 + lane];
    wreg[8 + q][16] = 0.f;
    bsum[8 + q] = bi2[R] + bh2[R];
  }
  // projection weights: wave 2 of blocks 0..63 holds w_out row `bid`
  float wp[16];
  float bz = 0.f;
  if (bid < 64 && wv == 2) {
#pragma unroll
    for (int k = 0; k < 16; ++k) wp[k] = w_out[(size_t)bid * 1024 + k * 64 + lane];
    bz = b_out[bid];
  }

  for (int s = 0; s < NSTAGES; ++s) {
    const float* hb = h_buf + (s & 1) * 1536;
    const int p1 = s - 3, p2 = s - 4, p3 = s - 5, p4 = s - 6,
              p5 = s - 7, p6 = s - 8, p7 = s - 9;

    // ---- pre-barrier LDS staging ----
    if (p1 >= 0 && p1 < NPOS) {
      const float* rr = rnn_ring + (p1 & 7) * 512;
      sro[tid]       = aload(rr + tid);
      sro[tid + 256] = aload(rr + tid + 256);
    }
    if (p3 >= 0 && p3 < NPOS && tid < 16)
      swex[tid] = aload(w_ring + (p3 & 1) * 2048 + bid * 16 + tid);

    // ---- LSTM: gather inputs, register dot products (all 4 waves) ----
    {
      float hh[24];   // h0|h1|h2 from previous stage
      if (s < NPOS + 2) {
#pragma unroll
        for (int k = 0; k < 24; ++k) hh[k] = aload(hb + k * 64 + lane);
      }
      if (s < NPOS) {   // layer 0 at position s
        float x0[9];
        const int b0 = s & 31, t0 = s >> 5;
        const int g0 = gt[b0 * LL + t0];
        if (t0 == 0) {
          x0[0] = (lane == g0) ? 1.f : 0.f;
          const float* cb = ctx_t + (size_t)b0 * TT * HIDN;
#pragma unroll
          for (int k = 0; k < 8; ++k) x0[1 + k] = cb[k * 64 + lane];
        } else {
          x0[0] = emb[g0 * 64 + lane];
          const float* cr = ctx_ring + ((s - 32) & 63) * 512;
#pragma unroll
          for (int k = 0; k < 8; ++k) x0[1 + k] = aload(cr + k * 64 + lane);
        }
#pragma unroll
        for (int q = 0; q < 4; ++q) {
          float a = 0.f;
#pragma unroll
          for (int k = 0; k < 9; ++k) a += wreg[q][k] * x0[k];
#pragma unroll
          for (int k = 0; k < 8; ++k) a += wreg[q][9 + k] * hh[k];
          a = wsum(a) + bsum[q];
          if (lane == 0) gates[wv * 4 + q] = a;
        }
      }
      if (s >= 1 && s - 1 < NPOS) {  // layer 1 at position s-1: input h0, recur h1
#pragma unroll
        for (int q = 0; q < 4; ++q) {
          float a = 0.f;
#pragma unroll
          for (int k = 0; k < 16; ++k) a += wreg[4 + q][k] * hh[k];
          a = wsum(a) + bsum[4 + q];
          if (lane == 0) gates[16 + wv * 4 + q] = a;
        }
      }
      if (s >= 2 && s - 2 < NPOS) {  // layer 2 at position s-2: input h1, recur h2
#pragma unroll
        for (int q = 0; q < 4; ++q) {
          float a = 0.f;
#pragma unroll
          for (int k = 0; k < 16; ++k) a += wreg[8 + q][k] * hh[8 + k];
          a = wsum(a) + bsum[8 + q];
          if (lane == 0) gates[32 + wv * 4 + q] = a;
        }
      }
    }
    __syncthreads();  // gates, sro, swex visible block-wide

    // ---- pointwise cell update (4 units x 3 layers) ----
    if (tid < 12) {
      const int l = tid >> 2, q = tid & 3;
      const int pl = s - l;
      if (pl >= 0 && pl < NPOS) {
        const float gi = gates[l * 16 + q];
        const float gf = gates[l * 16 + 4 + q];
        const float gg = gates[l * 16 + 8 + q];
        const float go = gates[l * 16 + 12 + q];
        const float cn = sigm(gf) * csto[tid] + sigm(gi) * tanhf(gg);
        const float hn = sigm(go) * tanhf(cn);
        csto[tid] = cn;
        const int u = ub + q;
        astore(h_buf + ((s + 1) & 1) * 1536 + l * 512 + u, hn);
        if (l == 2) astore(rnn_ring + (pl & 7) * 512 + u, hn);
      }
    }

    // ---- attn A: energies, 16 T-rows per block (4 per wave) ----
    if (p1 >= 0 && p1 < NPOS) {
      const int b1 = p1 & 31;
#pragma unroll
      for (int jj = 0; jj < 4; ++jj) {
        const int j = bid * 16 + wv * 4 + jj;
        const float* crow = ctx_t + ((size_t)b1 * TT + j) * HIDN;
        float a = 0.f;
#pragma unroll
        for (int k = 0; k < 8; ++k) a += crow[k * 64 + lane] * sro[k * 64 + lane];
        a = wsum(a);
        if (lane == 0) astore(e_ring + (p1 & 1) * 2048 + j, a);
      }
    }

    // ---- attn C: weighted partial sum, 16 rows per block, 2 dims/thread ----
    if (p3 >= 0 && p3 < NPOS) {
      const int b3 = p3 & 31;
      const float* cb3 = ctx_t + ((size_t)b3 * TT + bid * 16) * HIDN;
      float a0 = 0.f, a1 = 0.f;
#pragma unroll
      for (int j = 0; j < 16; ++j) {
        a0 += swex[j] * cb3[j * HIDN + tid];
        a1 += swex[j] * cb3[j * HIDN + tid + 256];
      }
      float* Pb = P_ring + (p3 & 1) * (128 * 512) + bid * 512;
      astore(Pb + tid, a0);
      astore(Pb + tid + 256, a1);
    }

    // ---- attn D1: 128 -> 16 partial combine (blocks 0..15) ----
    if (bid < 16 && p4 >= 0 && p4 < NPOS) {
      const float* Pb = P_ring + (p4 & 1) * (128 * 512) + (bid * 8) * 512;
      float q0 = 0.f, q1 = 0.f;
#pragma unroll
      for (int k = 0; k < 8; ++k) {
        q0 += aload(Pb + k * 512 + tid);
        q1 += aload(Pb + k * 512 + tid + 256);
      }
      float* Qb = Q_ring + (p4 & 1) * 8192 + bid * 512;
      astore(Qb + tid, q0);
      astore(Qb + tid + 256, q1);
    }

    // ---- attn D2: 16 -> 1 combine (block 16) ----
    if (bid == 16 && p5 >= 0 && p5 < NPOS) {
      const float* Qb = Q_ring + (p5 & 1) * 8192;
      float c0 = 0.f, c1 = 0.f;
#pragma unroll
      for (int k = 0; k < 16; ++k) {
        c0 += aload(Qb + k * 512 + tid);
        c1 += aload(Qb + k * 512 + tid + 256);
      }
      float* cr = ctx_ring + (p5 & 63) * 512;
      astore(cr + tid, c0);
      astore(cr + tid + 256, c1);
    }

    // ---- attn B: global softmax over 2048 energies (block 17, wave 3) ----
    if (bid == 17 && wv == 3 && p2 >= 0 && p2 < NPOS) {
      const float* eb = e_ring + (p2 & 1) * 2048;
      float e[32];
#pragma unroll
      for (int k = 0; k < 32; ++k) e[k] = aload(eb + k * 64 + lane);
      float m = e[0];
#pragma unroll
      for (int k = 1; k < 32; ++k) m = fmaxf(m, e[k]);
      m = wmax(m);
      float ssum = 0.f;
#pragma unroll
      for (int k = 0; k < 32; ++k) { e[k] = expf(e[k] - m); ssum += e[k]; }
      ssum = wsum(ssum);
      const float inv = 1.f / ssum;
      float* wb = w_ring + (p2 & 1) * 2048;
#pragma unroll
      for (int k = 0; k < 32; ++k) astore(wb + k * 64 + lane, e[k] * inv);
    }

    // ---- proj1: z[v] = w_out[v] . [rnn|ctx] (wave 2 of blocks 0..63) ----
    if (bid < 64 && wv == 2 && p6 >= 0 && p6 < NPOS) {
      const float* rr6 = rnn_ring + (p6 & 7) * 512;
      const float* cr6 = ctx_ring + (p6 & 63) * 512;
      float a = 0.f;
#pragma unroll
      for (int k = 0; k < 8; ++k) a += wp[k] * aload(rr6 + k * 64 + lane);
#pragma unroll
      for (int k = 0; k < 8; ++k) a += wp[8 + k] * aload(cr6 + k * 64 + lane);
      a = wsum(a);
      if (lane == 0) astore(z_ring + (p6 & 1) * 64 + bid, a + bz);
    }

    // ---- proj2: log_softmax + output write (block 18, wave 3) ----
    if (bid == 18 && wv == 3 && p7 >= 0 && p7 < NPOS) {
      const float z = aload(z_ring + (p7 & 1) * 64 + lane);
      const float M = wmax(z);
      const float ls = M + logf(wsum(expf(z - M)));
      out[((size_t)(p7 & 31) * 99 + (p7 >> 5)) * 64 + lane] = z - ls;
    }

    // ---- grid barrier (r4-proven): per-wave vmem drain + acq/rel flags ----
    asm volatile("s_waitcnt vmcnt(0)" ::: "memory");
    __syncthreads();
    if (tid == 0)
      __hip_atomic_store(arrive + bid, s + 1, __ATOMIC_RELEASE, __HIP_MEMORY_SCOPE_AGENT);
    if (tid < NBLK)
      while (__hip_atomic_load(arrive + tid, __ATOMIC_ACQUIRE, __HIP_MEMORY_SCOPE_AGENT) < s + 1)
        __builtin_amdgcn_s_sleep(2);
    __syncthreads();
  }
}

extern "C" void kernel_launch(void* const* d_in, const int* in_sizes, int n_in,
                              void* d_out, int out_size, void* d_ws, size_t ws_size,
                              hipStream_t stream) {
  (void)in_sizes; (void)n_in; (void)out_size; (void)ws_size;
  const float* ctx_t = (const float*)d_in[0];
  const int*   gt    = (const int*)d_in[1];
  const float* emb   = (const float*)d_in[3];
  const float* w_out = (const float*)d_in[4];
  const float* b_out = (const float*)d_in[5];
  const float* wi0 = (const float*)d_in[6];
  const float* wh0 = (const float*)d_in[7];
  const float* bi0 = (const float*)d_in[8];
  const float* bh0 = (const float*)d_in[9];
  const float* wi1 = (const float*)d_in[10];
  const float* wh1 = (const float*)d_in[11];
  const float* bi1 = (const float*)d_in[12];
  const float* bh1 = (const float*)d_in[13];
  const float* wi2 = (const float*)d_in[14];
  const float* wh2 = (const float*)d_in[15];
  const float* bi2 = (const float*)d_in[16];
  const float* bh2 = (const float*)d_in[17];
  float* out = (float*)d_out;
  float* ws  = (float*)d_ws;

  hipLaunchKernelGGL(speller_init, dim3(13), dim3(256), 0, stream, ws);

  // Plain (non-cooperative) launch: 128 blocks on 256 CUs are always
  // co-resident; the barrier is hand-rolled flags, no cg::sync needed.
  hipLaunchKernelGGL(speller_main, dim3(NBLK), dim3(NTHR), 0, stream,
                     ctx_t, gt, emb, w_out, b_out,
                     wi0, wh0, bi0, bh0,
                     wi1, wh1, bi1, bh1,
                     wi2, wh2, bi2, bh2,
                     out, ws);
}

// Round 9
// 24709.216 us; speedup vs baseline: 5.8744x; 5.8744x over previous
//
#include <hip/hip_runtime.h>
#include <math.h>

#define NBLK 128
#define NTHR 512
#define NPOS 3168     // 99 steps * 32 batch
#define NSTAGES 3177  // last proj-phase2 at s = 3167 + 9
#define HIDN 512
#define TT 2048
#define LL 100

__device__ __forceinline__ float aload(const float* p) {
  return __hip_atomic_load((float*)p, __ATOMIC_RELAXED, __HIP_MEMORY_SCOPE_AGENT);
}
__device__ __forceinline__ void astore(float* p, float v) {
  __hip_atomic_store(p, v, __ATOMIC_RELAXED, __HIP_MEMORY_SCOPE_AGENT);
}
__device__ __forceinline__ int aload_i(const int* p) {
  return __hip_atomic_load((int*)p, __ATOMIC_RELAXED, __HIP_MEMORY_SCOPE_AGENT);
}
__device__ __forceinline__ void astore_i(int* p, int v) {
  __hip_atomic_store(p, v, __ATOMIC_RELAXED, __HIP_MEMORY_SCOPE_AGENT);
}
__device__ __forceinline__ float wsum(float v) {
#pragma unroll
  for (int o = 32; o; o >>= 1) v += __shfl_xor(v, o);
  return v;
}
__device__ __forceinline__ float wmax(float v) {
#pragma unroll
  for (int o = 32; o; o >>= 1) v = fmaxf(v, __shfl_xor(v, o));
  return v;
}
__device__ __forceinline__ float sigm(float x) { return 1.f / (1.f + expf(-x)); }

extern "C" __global__ void speller_init(float* ws) {
  const int i = blockIdx.x * blockDim.x + threadIdx.x;
  if (i < 5120) ws[i] = 0.f;  // padded arrive flags (2048 ints) + h double buffers (3072 floats)
}

extern "C" __global__ __launch_bounds__(NTHR, 2)
void speller_main(const float* __restrict__ ctx_t, const int* __restrict__ gt,
                  const float* __restrict__ emb, const float* __restrict__ w_out,
                  const float* __restrict__ b_out,
                  const float* __restrict__ wi0, const float* __restrict__ wh0,
                  const float* __restrict__ bi0, const float* __restrict__ bh0,
                  const float* __restrict__ wi1, const float* __restrict__ wh1,
                  const float* __restrict__ bi1, const float* __restrict__ bh1,
                  const float* __restrict__ wi2, const float* __restrict__ wh2,
                  const float* __restrict__ bi2, const float* __restrict__ bh2,
                  float* __restrict__ out, float* __restrict__ ws)
{
  const int bid = blockIdx.x, tid = threadIdx.x;
  const int lane = tid & 63, wv = tid >> 6;
  const int ub = bid * 4;  // this block's 4 hidden units (per layer)

  // ---------------- workspace layout (197,760 floats = 791 KB) ----------------
  int*   arrive   = (int*)ws;               // [128][16] one cacheline per block
  float* h_buf    = ws + 2048;              // [2][3][512]
  float* rnn_ring = ws + 5120;              // [8][512]
  float* ctx_ring = ws + 9216;              // [64][512]
  float* e_ring   = ws + 41984;             // [2][2048]
  float* w_ring   = ws + 46080;             // [2][2048]
  float* P_ring   = ws + 50176;             // [2][128][512]
  float* Q_ring   = ws + 181248;            // [2][16][512]
  float* z_ring   = ws + 197632;            // [2][64]

  __shared__ float sro[HIDN];   // rnn_out for attention energies
  __shared__ float swex[16];    // this block's 16 attention weights (phase C)
  __shared__ float gates[48];   // l*16 + g*4 + q
  __shared__ float csto[12];    // cell state, 4 units x 3 layers

  if (tid < 12) csto[tid] = 0.f;

  // ---------------- weight preload into VGPRs ----------------
  // waves 0,1: layer 0 (gates {0,1}/{2,3} x 4 units, 17 chunks incl. emb)
  // waves 2,3: layer 1 ; waves 4,5: layer 2 (16 chunks)
  const int lyr = wv >> 1;  // 0..2 for wv 0..5
  float wreg[8][17];
  float bsum[8];
  if (wv < 6) {
    if (lyr == 0) {
#pragma unroll
      for (int r = 0; r < 8; ++r) {
        const int R = (wv * 2 + (r >> 2)) * 512 + ub + (r & 3);
#pragma unroll
        for (int k = 0; k < 9; ++k) wreg[r][k] = wi0[(size_t)R * 576 + k * 64 + lane];
#pragma unroll
        for (int k = 0; k < 8; ++k) wreg[r][9 + k] = wh0[(size_t)R * 512 + k * 64 + lane];
        bsum[r] = bi0[R] + bh0[R];
      }
    } else {
      const float* wiL = (lyr == 1) ? wi1 : wi2;
      const float* whL = (lyr == 1) ? wh1 : wh2;
      const float* biL = (lyr == 1) ? bi1 : bi2;
      const float* bhL = (lyr == 1) ? bh1 : bh2;
#pragma unroll
      for (int r = 0; r < 8; ++r) {
        const int R = ((wv & 1) * 2 + (r >> 2)) * 512 + ub + (r & 3);
#pragma unroll
        for (int k = 0; k < 8; ++k) wreg[r][k] = wiL[(size_t)R * 512 + k * 64 + lane];
#pragma unroll
        for (int k = 0; k < 8; ++k) wreg[r][8 + k] = whL[(size_t)R * 512 + k * 64 + lane];
        bsum[r] = biL[R] + bhL[R];
      }
    }
  }
  // projection weights: wave 6 of blocks 0..63 holds w_out row `bid`
  float wp[16];
  float bz = 0.f;
  if (bid < 64 && wv == 6) {
#pragma unroll
    for (int k = 0; k < 16; ++k) wp[k] = w_out[(size_t)bid * 1024 + k * 64 + lane];
    bz = b_out[bid];
  }

  for (int s = 0; s < NSTAGES; ++s) {
    const float* hb = h_buf + (s & 1) * 1536;
    const int p1 = s - 3, p2 = s - 4, p3 = s - 5, p4 = s - 6,
              p5 = s - 7, p6 = s - 8, p7 = s - 9;

    // ---- pre-barrier LDS staging ----
    if (p1 >= 0 && p1 < NPOS) sro[tid] = aload(rnn_ring + (p1 & 7) * 512 + tid);
    if (p3 >= 0 && p3 < NPOS && tid < 16)
      swex[tid] = aload(w_ring + (p3 & 1) * 2048 + bid * 16 + tid);

    // ---- LSTM gather + register dot products (waves 0..5) ----
    if (wv < 6) {
      const int pL = s - lyr;
      if (pL >= 0 && pL < NPOS) {
        float x[17];
        if (lyr == 0) {
          const int b0 = s & 31, t0 = s >> 5;
          const int g0 = gt[b0 * LL + t0];
          if (t0 == 0) {
            x[0] = (lane == g0) ? 1.f : 0.f;
            const float* cb = ctx_t + (size_t)b0 * TT * HIDN;
#pragma unroll
            for (int k = 0; k < 8; ++k) x[1 + k] = cb[k * 64 + lane];
          } else {
            x[0] = emb[g0 * 64 + lane];
            const float* cr = ctx_ring + ((s - 32) & 63) * 512;
#pragma unroll
            for (int k = 0; k < 8; ++k) x[1 + k] = aload(cr + k * 64 + lane);
          }
#pragma unroll
          for (int k = 0; k < 8; ++k) x[9 + k] = aload(hb + k * 64 + lane);
#pragma unroll
          for (int r = 0; r < 8; ++r) {
            float a = 0.f;
#pragma unroll
            for (int k = 0; k < 17; ++k) a += wreg[r][k] * x[k];
            a = wsum(a) + bsum[r];
            if (lane == 0) gates[(wv * 2 + (r >> 2)) * 4 + (r & 3)] = a;
          }
        } else {
          const int base = (lyr - 1) * 512;  // input = h_{lyr-1}, recur = h_{lyr}
          float xx[16];
#pragma unroll
          for (int k = 0; k < 8; ++k) xx[k]     = aload(hb + base + k * 64 + lane);
#pragma unroll
          for (int k = 0; k < 8; ++k) xx[8 + k] = aload(hb + base + 512 + k * 64 + lane);
#pragma unroll
          for (int r = 0; r < 8; ++r) {
            float a = 0.f;
#pragma unroll
            for (int k = 0; k < 16; ++k) a += wreg[r][k] * xx[k];
            a = wsum(a) + bsum[r];
            if (lane == 0) gates[lyr * 16 + ((wv & 1) * 2 + (r >> 2)) * 4 + (r & 3)] = a;
          }
        }
      }
    }
    __syncthreads();  // gates, sro, swex visible block-wide

    // ---- pointwise cell update (4 units x 3 layers) ----
    if (tid < 12) {
      const int l = tid >> 2, q = tid & 3;
      const int pl = s - l;
      if (pl >= 0 && pl < NPOS) {
        const float gi = gates[l * 16 + q];
        const float gf = gates[l * 16 + 4 + q];
        const float gg = gates[l * 16 + 8 + q];
        const float go = gates[l * 16 + 12 + q];
        const float cn = sigm(gf) * csto[tid] + sigm(gi) * tanhf(gg);
        const float hn = sigm(go) * tanhf(cn);
        csto[tid] = cn;
        const int u = ub + q;
        astore(h_buf + ((s + 1) & 1) * 1536 + l * 512 + u, hn);
        if (l == 2) astore(rnn_ring + (pl & 7) * 512 + u, hn);
      }
    }

    // ---- attn A: energies, 16 T-rows per block (2 per wave) ----
    if (p1 >= 0 && p1 < NPOS) {
      const int b1 = p1 & 31;
#pragma unroll
      for (int jj = 0; jj < 2; ++jj) {
        const int j = bid * 16 + wv * 2 + jj;
        const float* crow = ctx_t + ((size_t)b1 * TT + j) * HIDN;
        float a = 0.f;
#pragma unroll
        for (int k = 0; k < 8; ++k) a += crow[k * 64 + lane] * sro[k * 64 + lane];
        a = wsum(a);
        if (lane == 0) astore(e_ring + (p1 & 1) * 2048 + j, a);
      }
    }

    // ---- attn C: weighted partial sum, 16 rows per block (waves spread 512thr) ----
    if (p3 >= 0 && p3 < NPOS) {
      const int b3 = p3 & 31;
      const float* cb3 = ctx_t + ((size_t)b3 * TT + bid * 16) * HIDN;
      float* Pb = P_ring + (p3 & 1) * (128 * 512) + bid * 512;
      for (int c = tid; c < 512; c += NTHR) {
        float a0 = 0.f;
#pragma unroll
        for (int j = 0; j < 16; ++j) a0 += swex[j] * cb3[j * HIDN + c];
        astore(Pb + c, a0);
      }
    }

    // ---- attn D1: 128 -> 16 partial combine (blocks 0..15) ----
    if (bid < 16 && p4 >= 0 && p4 < NPOS) {
      const float* Pb = P_ring + (p4 & 1) * (128 * 512) + (bid * 8) * 512;
      float* Qb = Q_ring + (p4 & 1) * 8192 + bid * 512;
      for (int c = tid; c < 512; c += NTHR) {
        float q0 = 0.f;
#pragma unroll
        for (int k = 0; k < 8; ++k) q0 += aload(Pb + k * 512 + c);
        astore(Qb + c, q0);
      }
    }

    // ---- attn D2: 16 -> 1 combine (block 16) ----
    if (bid == 16 && p5 >= 0 && p5 < NPOS) {
      const float* Qb = Q_ring + (p5 & 1) * 8192;
      float* cr = ctx_ring + (p5 & 63) * 512;
      for (int c = tid; c < 512; c += NTHR) {
        float c0 = 0.f;
#pragma unroll
        for (int k = 0; k < 16; ++k) c0 += aload(Qb + k * 512 + c);
        astore(cr + c, c0);
      }
    }

    // ---- attn B: global softmax over 2048 energies (block 17, wave 7) ----
    if (bid == 17 && wv == 7 && p2 >= 0 && p2 < NPOS) {
      const float* eb = e_ring + (p2 & 1) * 2048;
      float e[32];
#pragma unroll
      for (int k = 0; k < 32; ++k) e[k] = aload(eb + k * 64 + lane);
      float m = e[0];
#pragma unroll
      for (int k = 1; k < 32; ++k) m = fmaxf(m, e[k]);
      m = wmax(m);
      float ssum = 0.f;
#pragma unroll
      for (int k = 0; k < 32; ++k) { e[k] = expf(e[k] - m); ssum += e[k]; }
      ssum = wsum(ssum);
      const float inv = 1.f / ssum;
      float* wb = w_ring + (p2 & 1) * 2048;
#pragma unroll
      for (int k = 0; k < 32; ++k) astore(wb + k * 64 + lane, e[k] * inv);
    }

    // ---- proj1: z[v] = w_out[v] . [rnn|ctx] (wave 6 of blocks 0..63) ----
    if (bid < 64 && wv == 6 && p6 >= 0 && p6 < NPOS) {
      const float* rr6 = rnn_ring + (p6 & 7) * 512;
      const float* cr6 = ctx_ring + (p6 & 63) * 512;
      float a = 0.f;
#pragma unroll
      for (int k = 0; k < 8; ++k) a += wp[k] * aload(rr6 + k * 64 + lane);
#pragma unroll
      for (int k = 0; k < 8; ++k) a += wp[8 + k] * aload(cr6 + k * 64 + lane);
      a = wsum(a);
      if (lane == 0) astore(z_ring + (p6 & 1) * 64 + bid, a + bz);
    }

    // ---- proj2: log_softmax + output write (block 18, wave 7) ----
    if (bid == 18 && wv == 7 && p7 >= 0 && p7 < NPOS) {
      const float z = aload(z_ring + (p7 & 1) * 64 + lane);
      const float M = wmax(z);
      const float ls = M + logf(wsum(expf(z - M)));
      out[((size_t)(p7 & 31) * 99 + (p7 >> 5)) * 64 + lane] = z - ls;
    }

    // ---- grid barrier: RELAXED flags, no per-poll cache maintenance ----
    // Ordering argument: all cross-block data moves via agent-scope atomics
    // (coherence-point ops, L1-bypassing). Each wave drains its own stores
    // with vmcnt(0) BEFORE syncthreads, so all block data is globally visible
    // before tid 0's flag store issues. Polls are relaxed loads (no
    // buffer_inv per iteration); a compiler fence pins program order after.
    asm volatile("s_waitcnt vmcnt(0)" ::: "memory");
    __syncthreads();
    if (tid == 0) astore_i(arrive + bid * 16, s + 1);
    if (tid < NBLK)
      while (aload_i(arrive + tid * 16) < s + 1) __builtin_amdgcn_s_sleep(1);
    asm volatile("" ::: "memory");
    __syncthreads();
  }
}

extern "C" void kernel_launch(void* const* d_in, const int* in_sizes, int n_in,
                              void* d_out, int out_size, void* d_ws, size_t ws_size,
                              hipStream_t stream) {
  (void)in_sizes; (void)n_in; (void)out_size; (void)ws_size;
  const float* ctx_t = (const float*)d_in[0];
  const int*   gt    = (const int*)d_in[1];
  const float* emb   = (const float*)d_in[3];
  const float* w_out = (const float*)d_in[4];
  const float* b_out = (const float*)d_in[5];
  const float* wi0 = (const float*)d_in[6];
  const float* wh0 = (const float*)d_in[7];
  const float* bi0 = (const float*)d_in[8];
  const float* bh0 = (const float*)d_in[9];
  const float* wi1 = (const float*)d_in[10];
  const float* wh1 = (const float*)d_in[11];
  const float* bi1 = (const float*)d_in[12];
  const float* bh1 = (const float*)d_in[13];
  const float* wi2 = (const float*)d_in[14];
  const float* wh2 = (const float*)d_in[15];
  const float* bi2 = (const float*)d_in[16];
  const float* bh2 = (const float*)d_in[17];
  float* out = (float*)d_out;
  float* ws  = (float*)d_ws;

  hipLaunchKernelGGL(speller_init, dim3(20), dim3(256), 0, stream, ws);

  // Plain (non-cooperative) launch: 128 blocks on 256 CUs are always
  // co-resident; the barrier is hand-rolled flags (r8 validated).
  hipLaunchKernelGGL(speller_main, dim3(NBLK), dim3(NTHR), 0, stream,
                     ctx_t, gt, emb, w_out, b_out,
                     wi0, wh0, bi0, bh0,
                     wi1, wh1, bi1, bh1,
                     wi2, wh2, bi2, bh2,
                     out, ws);
}